// Round 14
// baseline (78.391 us; speedup 1.0000x reference)
//
#include <hip/hip_runtime.h>
#include <cstdint>
#include <cstddef>

// ---------------------------------------------------------------------------
// BasicLSTM fused kernel for MI355X (gfx950) — round 14.
//   pre_g = X @ W_g + H @ U_g + b_g   for g in {f, i, o}
//   c_new = sig(pre_f)*c0 + sig(pre_f)*sig(pre_i)     (input_cell == forget!)
//   h_new = sig(pre_o)*tanh(c_new)
// Round-14 = R11/R13 schedule (2-phase/K-tile, counted vmcnt, best so far)
// with ONE lever: 16x16x32 -> 32x32x16 MFMA.
//   - 32x32 runs at 4060 FLOP/cyc vs 3378 (m119): +20% matrix-pipe efficiency,
//     half the MFMA instruction count (12/phase vs 24). LDS traffic unchanged.
//   - Gates repacked in 32-col triples: pcol = (n>>5)*96 + g*32 + (n&31).
//   - Wave = 64 rows x 96 pcols = 2 m-frags x 3 gate-frags; acc 6 x f32x16.
//   - A-frag: row=lane&31, k=(lane>>5)*8+j (K-doubled lane map, mirrors our
//     verified 16x16x32 usage). C/D: col=lane&31,
//     row=(reg&3)+8*(reg>>2)+4*(lane>>5)  [m74/m101 verified].
//   Staging, LDS image, swizzle, vmcnt accounting: byte-identical to R13.
// ---------------------------------------------------------------------------

typedef __attribute__((ext_vector_type(8))) short bf16x8;
typedef __attribute__((ext_vector_type(16))) float f32x16;
typedef __attribute__((ext_vector_type(8))) short s16x8;
typedef __attribute__((ext_vector_type(4))) float f32x4v;

#define MROWS 4096
#define KD    1024
#define KALL  2048
#define NC    1024

__device__ __forceinline__ short f2bf(float f) {
    uint32_t u = __builtin_bit_cast(uint32_t, f);
    u += 0x7fffu + ((u >> 16) & 1u);   // round-to-nearest-even
    return (short)(u >> 16);
}

// ---- X,H fp32 -> Ab[4096][2048] bf16 (X in k 0..1023, H in k 1024..2047) ---
__global__ void cvt_bf16_kernel(const float* __restrict__ x,
                                const float* __restrict__ h,
                                short* __restrict__ ab) {
    int b = blockIdx.x;
    const float* in;
    int coff;
    if (b < 2048) { in = x; coff = 0; }
    else          { in = h; coff = KD; b -= 2048; }
    const int i = (b * 256 + threadIdx.x) * 8;
    const int row = i >> 10, col = i & 1023;
    f32x4v a = *(const f32x4v*)(in + i);
    f32x4v c = *(const f32x4v*)(in + i + 4);
    s16x8 o;
    o[0] = f2bf(a[0]); o[1] = f2bf(a[1]); o[2] = f2bf(a[2]); o[3] = f2bf(a[3]);
    o[4] = f2bf(c[0]); o[5] = f2bf(c[1]); o[6] = f2bf(c[2]); o[7] = f2bf(c[3]);
    *(s16x8*)(ab + (size_t)row * KALL + coff + col) = o;
}

// ---- pack 6 weights into Bp[3072][2048] bf16, 32-col gate triples ---------
struct W6 { const float* src[6]; };

__global__ void pack_w_kernel(W6 p, short* __restrict__ bp) {
    __shared__ short tile[32][33];   // [k_local][n_local]
    const int z = blockIdx.z;                 // 0..5 = wf,wi,wo,uf,ui,uo
    const float* __restrict__ w = p.src[z];
    const int g    = (z < 3) ? z : z - 3;
    const int koff = (z < 3) ? 0 : KD;
    const int tx = threadIdx.x & 31;
    const int ty = threadIdx.x >> 5;          // 0..7
    const int kbase = blockIdx.y * 32;
    const int nbase = blockIdx.x * 32;
#pragma unroll
    for (int r = 0; r < 4; ++r) {
        int k = kbase + ty + r * 8;
        tile[ty + r * 8][tx] = f2bf(w[k * NC + nbase + tx]);
    }
    __syncthreads();
#pragma unroll
    for (int r = 0; r < 4; ++r) {
        const int n = nbase + ty + r * 8;
        const int pcol = ((n >> 5) * 3 + g) * 32 + (n & 31);
        bp[(size_t)pcol * KALL + koff + kbase + tx] = tile[tx][ty + r * 8];
    }
}

// ---- fused 3-gate GEMM + LSTM cell (256x192, 2-phase/K-tile, 32x32 MFMA) --
// LDS per buffer (56 KB): A: [ks][mh][128 rows x 64B swz] = 4 x 8KB at 0;
//                         B: [ks][192 rows x 64B swz] = 2 x 12KB at 32768.
// Stage loads per K-tile (accounting order):
//   p0 issues: L0: A ks0 mh0 -> 0      L1: A ks0 mh1 -> 8192
//              L4: B bytes 0..8K -> 32768   L5: B bytes 8..16K -> 40960
//   p1 issues: L2: A ks1 mh0 -> 16384  L3: A ks1 mh1 -> 24576
//              L6: B bytes 16..24K -> 49152
// p0 consumes {L0,L1,L4,L5}; p1 consumes {L2,L3,L6}.
// Steady state 7 outstanding: vmcnt(3)@p0 entry, vmcnt(4)@p1 entry.
__global__ __launch_bounds__(512, 2)
void lstm_gemm_kernel(const short* __restrict__ Ab, const short* __restrict__ Bp,
                      const float* __restrict__ bf_, const float* __restrict__ bi_,
                      const float* __restrict__ bo_,
                      const float* __restrict__ c0,
                      float* __restrict__ outH, float* __restrict__ outC) {
    __shared__ __align__(16) char lds[2][57344];

    const int tid  = threadIdx.x;
    const int lane = tid & 63;
    const int wave = tid >> 6;            // 0..7
    const int wr   = wave >> 1;           // 0..3 (64-row group)
    const int wc   = wave & 1;            // 0..1 (96-pcol triple)
    const int m0   = blockIdx.y * 256;
    const int np0  = blockIdx.x * 192;

    const int l31  = lane & 31;
    const int half = lane >> 5;           // 0..1 (k-half of fragment)

    f32x16 acc[2][3] = {};   // [m-frag][gate] = 96 VGPRs

    // ---- staging thread constants (identical to R13) ----
    const int srow = tid >> 2;                              // 0..127
    const int skel = ((tid & 3) ^ ((tid >> 3) & 3)) * 8;    // swizzled k elems
    const short* aPtr[4];   // index = ks*2 + mh
#pragma unroll
    for (int l = 0; l < 4; ++l) {
        const int ks = l >> 1, mh = l & 1;
        aPtr[l] = Ab + (size_t)(m0 + mh * 128 + srow) * KALL + ks * 32 + skel;
    }
    const short* bPtr[3];
#pragma unroll
    for (int w = 0; w < 3; ++w) {
        const int pbyte = w * 8192 + tid * 16;
        const int ks  = pbyte / 12288;
        const int rem = pbyte - ks * 12288;
        const int row = rem >> 6;
        const int slot = (rem >> 4) & 3;
        bPtr[w] = Bp + (size_t)(np0 + row) * KALL + ks * 32 +
                  ((slot ^ ((row >> 1) & 3)) * 8);
    }

    // ---- read offsets (byte, within a buffer; ks0 base) ----
    // A frag (mf, kc): row r = wr*64 + mf*32 + l31; logical chunk kc*2+half.
    int aOffV[2][2];
#pragma unroll
    for (int mf = 0; mf < 2; ++mf)
#pragma unroll
        for (int kc = 0; kc < 2; ++kc) {
            const int r  = wr * 64 + mf * 32 + l31;
            const int r1 = r & 127;
            aOffV[mf][kc] = (r >> 7) * 8192 + r1 * 64 +
                            (((kc * 2 + half) ^ ((r1 >> 1) & 3)) << 4);
        }
    // B frag (g, kc): image row rb = wc*96 + g*32 + l31.
    int bOffV[3][2];
#pragma unroll
    for (int g = 0; g < 3; ++g)
#pragma unroll
        for (int kc = 0; kc < 2; ++kc) {
            const int rb = wc * 96 + g * 32 + l31;
            bOffV[g][kc] = 32768 + rb * 64 +
                           (((kc * 2 + half) ^ ((rb >> 1) & 3)) << 4);
        }

#define GLDS(SRC, DOFF)                                                      \
    __builtin_amdgcn_global_load_lds(                                        \
        (const __attribute__((address_space(1))) unsigned int*)(uintptr_t)(SRC), \
        (__attribute__((address_space(3))) unsigned int*)(uintptr_t)         \
            (Ls + (DOFF) + tid * 16), 16, 0, 0)

#define BAR    __builtin_amdgcn_s_barrier()
#define SCHED0 __builtin_amdgcn_sched_barrier(0)
#define LGKM0  asm volatile("s_waitcnt lgkmcnt(0)" ::: "memory")
#define WAITV(N) asm volatile("s_waitcnt vmcnt(" #N ")" ::: "memory")

#define MFMA12(AF, BG)                                                      \
    {                                                                       \
        __builtin_amdgcn_s_setprio(1);                                      \
        _Pragma("unroll")                                                   \
        for (int kc = 0; kc < 2; ++kc)                                      \
            _Pragma("unroll")                                               \
            for (int mf = 0; mf < 2; ++mf)                                  \
                _Pragma("unroll")                                           \
                for (int g = 0; g < 3; ++g)                                 \
                    acc[mf][g] = __builtin_amdgcn_mfma_f32_32x32x16_bf16(   \
                        AF[mf][kc], BG[g][kc], acc[mf][g], 0, 0, 0);        \
        __builtin_amdgcn_s_setprio(0);                                      \
    }

    // ---- prologue: tile 0's 7 loads in accounting order ----
    {
        char* Ls = lds[0];
        GLDS(aPtr[0], 0);      GLDS(aPtr[1], 8192);
        GLDS(bPtr[0], 32768);  GLDS(bPtr[1], 40960);
        GLDS(aPtr[2], 16384);  GLDS(aPtr[3], 24576);
        GLDS(bPtr[2], 49152);
    }

    bf16x8 af[2][2], bg[3][2];

    // ---- main loop: tiles 0..30, staging t+1 ----
    for (int t = 0; t < 31; ++t) {
        const char* L = lds[t & 1];
        char* Ls = lds[(t + 1) & 1];
        const int kb = (t + 1) * 64;

        // == p0: ks0 ==   (needs L0,L1,L4,L5 of t; 3 younger outstanding)
        WAITV(3);
        BAR;
        SCHED0;
#pragma unroll
        for (int mf = 0; mf < 2; ++mf)
#pragma unroll
            for (int kc = 0; kc < 2; ++kc)
                af[mf][kc] = *(const bf16x8*)(L + aOffV[mf][kc]);
#pragma unroll
        for (int g = 0; g < 3; ++g)
#pragma unroll
            for (int kc = 0; kc < 2; ++kc)
                bg[g][kc] = *(const bf16x8*)(L + bOffV[g][kc]);
        GLDS(aPtr[0] + kb, 0);
        GLDS(aPtr[1] + kb, 8192);
        GLDS(bPtr[0] + kb, 32768);
        GLDS(bPtr[1] + kb, 40960);
        SCHED0;
        LGKM0;
        SCHED0;
        MFMA12(af, bg);

        // == p1: ks1 ==   (needs L2,L3,L6 of t; 4 younger outstanding)
        WAITV(4);
        BAR;
        SCHED0;
#pragma unroll
        for (int mf = 0; mf < 2; ++mf)
#pragma unroll
            for (int kc = 0; kc < 2; ++kc)
                af[mf][kc] = *(const bf16x8*)(L + 16384 + aOffV[mf][kc]);
#pragma unroll
        for (int g = 0; g < 3; ++g)
#pragma unroll
            for (int kc = 0; kc < 2; ++kc)
                bg[g][kc] = *(const bf16x8*)(L + 12288 + bOffV[g][kc]);
        GLDS(aPtr[2] + kb, 16384);
        GLDS(aPtr[3] + kb, 24576);
        GLDS(bPtr[2] + kb, 49152);
        SCHED0;
        LGKM0;
        SCHED0;
        MFMA12(af, bg);
    }

    // ---- tail: tile 31, no staging ----
    {
        const char* L = lds[1];
        WAITV(3);
        BAR;
        SCHED0;
#pragma unroll
        for (int mf = 0; mf < 2; ++mf)
#pragma unroll
            for (int kc = 0; kc < 2; ++kc)
                af[mf][kc] = *(const bf16x8*)(L + aOffV[mf][kc]);
#pragma unroll
        for (int g = 0; g < 3; ++g)
#pragma unroll
            for (int kc = 0; kc < 2; ++kc)
                bg[g][kc] = *(const bf16x8*)(L + bOffV[g][kc]);
        LGKM0;
        SCHED0;
        MFMA12(af, bg);

        WAITV(0);
        BAR;
        SCHED0;
#pragma unroll
        for (int mf = 0; mf < 2; ++mf)
#pragma unroll
            for (int kc = 0; kc < 2; ++kc)
                af[mf][kc] = *(const bf16x8*)(L + 16384 + aOffV[mf][kc]);
#pragma unroll
        for (int g = 0; g < 3; ++g)
#pragma unroll
            for (int kc = 0; kc < 2; ++kc)
                bg[g][kc] = *(const bf16x8*)(L + 12288 + bOffV[g][kc]);
        LGKM0;
        SCHED0;
        MFMA12(af, bg);
    }

    // ---- fused LSTM epilogue (32x32 C/D: col=lane&31,
    //      row=(reg&3)+8*(reg>>2)+4*(lane>>5)) ----
    const int col = blockIdx.x * 64 + wc * 32 + l31;
    const float bfv = bf_[col], biv = bi_[col], bov = bo_[col];
#pragma unroll
    for (int mf = 0; mf < 2; ++mf) {
        const f32x16 pf = acc[mf][0];
        const f32x16 pi = acc[mf][1];
        const f32x16 po = acc[mf][2];
#pragma unroll
        for (int j = 0; j < 16; ++j) {
            const int row = m0 + wr * 64 + mf * 32 +
                            (j & 3) + 8 * (j >> 2) + 4 * half;
            const float fg = 1.f / (1.f + __expf(-(pf[j] + bfv)));
            const float ig = 1.f / (1.f + __expf(-(pi[j] + biv)));
            const float og = 1.f / (1.f + __expf(-(po[j] + bov)));
            const float cv = c0[row * NC + col];
            const float cn = fg * cv + fg * ig;   // input_cell == forget gate
            const float e  = __expf(-2.f * cn);
            const float th = (1.f - e) / (1.f + e);
            outH[row * NC + col] = og * th;
            outC[row * NC + col] = cn;
        }
    }
#undef GLDS
#undef BAR
#undef SCHED0
#undef LGKM0
#undef WAITV
#undef MFMA12
}

extern "C" void kernel_launch(void* const* d_in, const int* in_sizes, int n_in,
                              void* d_out, int out_size, void* d_ws, size_t ws_size,
                              hipStream_t stream) {
    const float* inputs = (const float*)d_in[0];
    const float* h0     = (const float*)d_in[1];
    const float* c0     = (const float*)d_in[2];
    const float* w_f    = (const float*)d_in[3];
    const float* u_f    = (const float*)d_in[4];
    const float* b_f    = (const float*)d_in[5];
    const float* w_i    = (const float*)d_in[6];
    const float* u_i    = (const float*)d_in[7];
    const float* b_i    = (const float*)d_in[8];
    const float* w_o    = (const float*)d_in[9];
    const float* u_o    = (const float*)d_in[10];
    const float* b_o    = (const float*)d_in[11];

    float* outH = (float*)d_out;
    float* outC = outH + (size_t)MROWS * NC;

    // workspace: Ab (16MB bf16) | Bp (12MB bf16)
    char* ws = (char*)d_ws;
    short* Ab = (short*)(ws);
    short* Bp = (short*)(ws + (16u << 20));

    cvt_bf16_kernel<<<4096, 256, 0, stream>>>(inputs, h0, Ab);

    W6 p;
    p.src[0] = w_f; p.src[1] = w_i; p.src[2] = w_o;
    p.src[3] = u_f; p.src[4] = u_i; p.src[5] = u_o;
    pack_w_kernel<<<dim3(32, 32, 6), 256, 0, stream>>>(p, Bp);

    // grid 16x16 = 256 blocks = 1/CU; id%8 = bx%8 -> same-B-panel blocks
    // share an XCD (B panel 768KB L2-resident).
    dim3 grid(16, 16);
    lstm_gemm_kernel<<<grid, 512, 0, stream>>>(
        Ab, Bp, b_f, b_i, b_o, c0, outH, outC);
}

// Round 15
// 72.917 us; speedup vs baseline: 1.0751x; 1.0751x over previous
//
#include <hip/hip_runtime.h>
#include <cstdint>
#include <cstddef>

// ---------------------------------------------------------------------------
// BasicLSTM fused kernel for MI355X (gfx950) — round 15 (revert to R13 best).
//   pre_g = X @ W_g + H @ U_g + b_g   for g in {f, i, o}
//   c_new = sig(pre_f)*c0 + sig(pre_f)*sig(pre_i)     (input_cell == forget!)
//   h_new = sig(pre_o)*tanh(c_new)
// R14's 32x32 MFMA produced 5.24M bank conflicts (4-way: 32-row frag reads
// have only 4 rotation slots per 64B row) -> reverted. R13 = best measured:
// GEMM ~60.4us (853 TF, ~94% of the plain-HIP 2-barrier structural ceiling),
// total ~73us, 0 conflicts.
// Structure: one GEMM Ab[4096][2048] x Bp[3072][2048] (gate-interleaved
// 16-col triples), 256x192 block tile, 4x2 wave grid (A-dup 2x, B-dup 4x:
// minimal 160KB LDS reads/K-tile), 2-phase/K-tile with counted vmcnt
// (>=2-phase load slack, never drained in main loop), 16x16x32 MFMA in
// 24-instr setprio clusters, chunk-rotation swizzle (conflict-free),
// fused LSTM epilogue.
// ---------------------------------------------------------------------------

typedef __attribute__((ext_vector_type(8))) short bf16x8;
typedef __attribute__((ext_vector_type(4))) float f32x4;
typedef __attribute__((ext_vector_type(8))) short s16x8;
typedef __attribute__((ext_vector_type(4))) float f32x4v;

#define MROWS 4096
#define KD    1024
#define KALL  2048
#define NC    1024

__device__ __forceinline__ short f2bf(float f) {
    uint32_t u = __builtin_bit_cast(uint32_t, f);
    u += 0x7fffu + ((u >> 16) & 1u);   // round-to-nearest-even
    return (short)(u >> 16);
}

// ---- X,H fp32 -> Ab[4096][2048] bf16 (X in k 0..1023, H in k 1024..2047) ---
__global__ void cvt_bf16_kernel(const float* __restrict__ x,
                                const float* __restrict__ h,
                                short* __restrict__ ab) {
    int b = blockIdx.x;
    const float* in;
    int coff;
    if (b < 2048) { in = x; coff = 0; }
    else          { in = h; coff = KD; b -= 2048; }
    const int i = (b * 256 + threadIdx.x) * 8;
    const int row = i >> 10, col = i & 1023;
    f32x4v a = *(const f32x4v*)(in + i);
    f32x4v c = *(const f32x4v*)(in + i + 4);
    s16x8 o;
    o[0] = f2bf(a[0]); o[1] = f2bf(a[1]); o[2] = f2bf(a[2]); o[3] = f2bf(a[3]);
    o[4] = f2bf(c[0]); o[5] = f2bf(c[1]); o[6] = f2bf(c[2]); o[7] = f2bf(c[3]);
    *(s16x8*)(ab + (size_t)row * KALL + coff + col) = o;
}

// ---- pack 6 weights into Bp[3072][2048] bf16, gate-interleaved cols -------
struct W6 { const float* src[6]; };

__global__ void pack_w_kernel(W6 p, short* __restrict__ bp) {
    __shared__ short tile[32][33];   // [k_local][n_local]
    const int z = blockIdx.z;                 // 0..5 = wf,wi,wo,uf,ui,uo
    const float* __restrict__ w = p.src[z];
    const int g    = (z < 3) ? z : z - 3;
    const int koff = (z < 3) ? 0 : KD;
    const int tx = threadIdx.x & 31;
    const int ty = threadIdx.x >> 5;          // 0..7
    const int kbase = blockIdx.y * 32;
    const int nbase = blockIdx.x * 32;
#pragma unroll
    for (int r = 0; r < 4; ++r) {
        int k = kbase + ty + r * 8;
        tile[ty + r * 8][tx] = f2bf(w[k * NC + nbase + tx]);
    }
    __syncthreads();
#pragma unroll
    for (int r = 0; r < 4; ++r) {
        const int n = nbase + ty + r * 8;
        const int pcol = ((n >> 4) * 3 + g) * 16 + (n & 15);
        bp[(size_t)pcol * KALL + koff + kbase + tx] = tile[tx][ty + r * 8];
    }
}

// ---- fused 3-gate GEMM + LSTM cell (256x192, 2-phase/K-tile) --------------
// LDS per buffer (56 KB): A: [ks][mh][128 rows x 64B swz] = 4 x 8KB at 0;
//                         B: [ks][192 rows x 64B swz] = 2 x 12KB at 32768.
// Stage loads per K-tile (accounting order):
//   p0 issues: L0: A ks0 mh0 -> 0      L1: A ks0 mh1 -> 8192
//              L4: B bytes 0..8K -> 32768   L5: B bytes 8..16K -> 40960
//   p1 issues: L2: A ks1 mh0 -> 16384  L3: A ks1 mh1 -> 24576
//              L6: B bytes 16..24K -> 49152
// p0 consumes {L0,L1,L4,L5}; p1 consumes {L2,L3,L6} (L5 retired at p0).
// Steady state 7 outstanding: vmcnt(3)@p0 entry, vmcnt(4)@p1 entry.
__global__ __launch_bounds__(512, 2)
void lstm_gemm_kernel(const short* __restrict__ Ab, const short* __restrict__ Bp,
                      const float* __restrict__ bf_, const float* __restrict__ bi_,
                      const float* __restrict__ bo_,
                      const float* __restrict__ c0,
                      float* __restrict__ outH, float* __restrict__ outC) {
    __shared__ __align__(16) char lds[2][57344];

    const int tid  = threadIdx.x;
    const int lane = tid & 63;
    const int wave = tid >> 6;            // 0..7
    const int wr   = wave >> 1;           // 0..3 (64-row group)
    const int wc   = wave & 1;            // 0..1 (96-pcol group)
    const int m0   = blockIdx.y * 256;
    const int np0  = blockIdx.x * 192;

    const int l15 = lane & 15;
    const int q   = lane >> 4;

    f32x4 acc[4][2][3] = {};   // [m][nt][gate] = 96 VGPRs

    // ---- staging thread constants ----
    const int srow = tid >> 2;                              // 0..127
    const int skel = ((tid & 3) ^ ((tid >> 3) & 3)) * 8;    // swizzled k elems
    const short* aPtr[4];   // index = ks*2 + mh
#pragma unroll
    for (int l = 0; l < 4; ++l) {
        const int ks = l >> 1, mh = l & 1;
        aPtr[l] = Ab + (size_t)(m0 + mh * 128 + srow) * KALL + ks * 32 + skel;
    }
    const short* bPtr[3];
#pragma unroll
    for (int w = 0; w < 3; ++w) {
        const int pbyte = w * 8192 + tid * 16;
        const int ks  = pbyte / 12288;
        const int rem = pbyte - ks * 12288;
        const int row = rem >> 6;
        const int slot = (rem >> 4) & 3;
        bPtr[w] = Bp + (size_t)(np0 + row) * KALL + ks * 32 +
                  ((slot ^ ((row >> 1) & 3)) * 8);
    }

    // ---- read offsets (byte, within a buffer; ks0 base) ----
    int aOffV[4];
#pragma unroll
    for (int m = 0; m < 4; ++m) {
        const int r = wr * 64 + m * 16 + l15;
        const int r1 = r & 127;
        aOffV[m] = (r >> 7) * 8192 + r1 * 64 + ((q ^ ((r1 >> 1) & 3)) << 4);
    }
    int bOffV[2][3];
#pragma unroll
    for (int nt = 0; nt < 2; ++nt)
#pragma unroll
        for (int g = 0; g < 3; ++g) {
            const int rb = (wc * 2 + nt) * 48 + g * 16 + l15;
            bOffV[nt][g] = 32768 + rb * 64 + ((q ^ ((rb >> 1) & 3)) << 4);
        }

#define GLDS(SRC, DOFF)                                                      \
    __builtin_amdgcn_global_load_lds(                                        \
        (const __attribute__((address_space(1))) unsigned int*)(uintptr_t)(SRC), \
        (__attribute__((address_space(3))) unsigned int*)(uintptr_t)         \
            (Ls + (DOFF) + tid * 16), 16, 0, 0)

#define BAR    __builtin_amdgcn_s_barrier()
#define SCHED0 __builtin_amdgcn_sched_barrier(0)
#define LGKM0  asm volatile("s_waitcnt lgkmcnt(0)" ::: "memory")
#define WAITV(N) asm volatile("s_waitcnt vmcnt(" #N ")" ::: "memory")

#define MFMA24(AF, BG)                                                       \
    {                                                                        \
        __builtin_amdgcn_s_setprio(1);                                       \
        _Pragma("unroll")                                                    \
        for (int mm = 0; mm < 4; ++mm)                                       \
            _Pragma("unroll")                                                \
            for (int nt = 0; nt < 2; ++nt)                                   \
                _Pragma("unroll")                                            \
                for (int g = 0; g < 3; ++g)                                  \
                    acc[mm][nt][g] = __builtin_amdgcn_mfma_f32_16x16x32_bf16(\
                        AF[mm], BG[nt][g], acc[mm][nt][g], 0, 0, 0);         \
        __builtin_amdgcn_s_setprio(0);                                       \
    }

    // ---- prologue: tile 0's 7 loads in accounting order ----
    {
        char* Ls = lds[0];
        GLDS(aPtr[0], 0);      GLDS(aPtr[1], 8192);
        GLDS(bPtr[0], 32768);  GLDS(bPtr[1], 40960);
        GLDS(aPtr[2], 16384);  GLDS(aPtr[3], 24576);
        GLDS(bPtr[2], 49152);
    }

    bf16x8 af[4], bg[2][3];

    // ---- main loop: tiles 0..30, staging t+1 ----
    for (int t = 0; t < 31; ++t) {
        const char* L = lds[t & 1];
        char* Ls = lds[(t + 1) & 1];
        const int kb = (t + 1) * 64;

        // == p0: ks0 ==   (needs L0,L1,L4,L5 of t; 3 younger outstanding)
        WAITV(3);
        BAR;
        SCHED0;
#pragma unroll
        for (int mm = 0; mm < 4; ++mm) af[mm] = *(const bf16x8*)(L + aOffV[mm]);
#pragma unroll
        for (int nt = 0; nt < 2; ++nt)
#pragma unroll
            for (int g = 0; g < 3; ++g)
                bg[nt][g] = *(const bf16x8*)(L + bOffV[nt][g]);
        GLDS(aPtr[0] + kb, 0);
        GLDS(aPtr[1] + kb, 8192);
        GLDS(bPtr[0] + kb, 32768);
        GLDS(bPtr[1] + kb, 40960);
        SCHED0;
        LGKM0;
        SCHED0;
        MFMA24(af, bg);

        // == p1: ks1 ==   (needs L2,L3,L6 of t; 4 younger outstanding)
        WAITV(4);
        BAR;
        SCHED0;
#pragma unroll
        for (int mm = 0; mm < 4; ++mm)
            af[mm] = *(const bf16x8*)(L + 16384 + aOffV[mm]);
#pragma unroll
        for (int nt = 0; nt < 2; ++nt)
#pragma unroll
            for (int g = 0; g < 3; ++g)
                bg[nt][g] = *(const bf16x8*)(L + 12288 + bOffV[nt][g]);
        GLDS(aPtr[2] + kb, 16384);
        GLDS(aPtr[3] + kb, 24576);
        GLDS(bPtr[2] + kb, 49152);
        SCHED0;
        LGKM0;
        SCHED0;
        MFMA24(af, bg);
    }

    // ---- tail: tile 31, no staging ----
    {
        const char* L = lds[1];
        WAITV(3);
        BAR;
        SCHED0;
#pragma unroll
        for (int mm = 0; mm < 4; ++mm) af[mm] = *(const bf16x8*)(L + aOffV[mm]);
#pragma unroll
        for (int nt = 0; nt < 2; ++nt)
#pragma unroll
            for (int g = 0; g < 3; ++g)
                bg[nt][g] = *(const bf16x8*)(L + bOffV[nt][g]);
        LGKM0;
        SCHED0;
        MFMA24(af, bg);

        WAITV(0);
        BAR;
        SCHED0;
#pragma unroll
        for (int mm = 0; mm < 4; ++mm)
            af[mm] = *(const bf16x8*)(L + 16384 + aOffV[mm]);
#pragma unroll
        for (int nt = 0; nt < 2; ++nt)
#pragma unroll
            for (int g = 0; g < 3; ++g)
                bg[nt][g] = *(const bf16x8*)(L + 12288 + bOffV[nt][g]);
        LGKM0;
        SCHED0;
        MFMA24(af, bg);
    }

    // ---- fused LSTM epilogue ----
    const int rj = q * 4;
#pragma unroll
    for (int m = 0; m < 4; ++m) {
#pragma unroll
        for (int nt = 0; nt < 2; ++nt) {
            const int col = blockIdx.x * 64 + (wc * 2 + nt) * 16 + l15;
            const float bfv = bf_[col], biv = bi_[col], bov = bo_[col];
            const f32x4 pf = acc[m][nt][0];
            const f32x4 pi = acc[m][nt][1];
            const f32x4 po = acc[m][nt][2];
#pragma unroll
            for (int j = 0; j < 4; ++j) {
                const int row = m0 + wr * 64 + m * 16 + rj + j;
                const float fg = 1.f / (1.f + __expf(-(pf[j] + bfv)));
                const float ig = 1.f / (1.f + __expf(-(pi[j] + biv)));
                const float og = 1.f / (1.f + __expf(-(po[j] + bov)));
                const float cv = c0[row * NC + col];
                const float cn = fg * cv + fg * ig;   // input_cell == forget gate
                const float e  = __expf(-2.f * cn);
                const float th = (1.f - e) / (1.f + e);
                outH[row * NC + col] = og * th;
                outC[row * NC + col] = cn;
            }
        }
    }
#undef GLDS
#undef BAR
#undef SCHED0
#undef LGKM0
#undef WAITV
#undef MFMA24
}

extern "C" void kernel_launch(void* const* d_in, const int* in_sizes, int n_in,
                              void* d_out, int out_size, void* d_ws, size_t ws_size,
                              hipStream_t stream) {
    const float* inputs = (const float*)d_in[0];
    const float* h0     = (const float*)d_in[1];
    const float* c0     = (const float*)d_in[2];
    const float* w_f    = (const float*)d_in[3];
    const float* u_f    = (const float*)d_in[4];
    const float* b_f    = (const float*)d_in[5];
    const float* w_i    = (const float*)d_in[6];
    const float* u_i    = (const float*)d_in[7];
    const float* b_i    = (const float*)d_in[8];
    const float* w_o    = (const float*)d_in[9];
    const float* u_o    = (const float*)d_in[10];
    const float* b_o    = (const float*)d_in[11];

    float* outH = (float*)d_out;
    float* outC = outH + (size_t)MROWS * NC;

    // workspace: Ab (16MB bf16) | Bp (12MB bf16)
    char* ws = (char*)d_ws;
    short* Ab = (short*)(ws);
    short* Bp = (short*)(ws + (16u << 20));

    cvt_bf16_kernel<<<4096, 256, 0, stream>>>(inputs, h0, Ab);

    W6 p;
    p.src[0] = w_f; p.src[1] = w_i; p.src[2] = w_o;
    p.src[3] = u_f; p.src[4] = u_i; p.src[5] = u_o;
    pack_w_kernel<<<dim3(32, 32, 6), 256, 0, stream>>>(p, Bp);

    // grid 16x16 = 256 blocks = 1/CU; id%8 = bx%8 -> same-B-panel blocks
    // share an XCD (B panel 768KB L2-resident).
    dim3 grid(16, 16);
    lstm_gemm_kernel<<<grid, 512, 0, stream>>>(
        Ab, Bp, b_f, b_i, b_o, c0, outH, outC);
}